// Round 9
// baseline (708.884 us; speedup 1.0000x reference)
//
#include <hip/hip_runtime.h>

typedef short bf16x8 __attribute__((ext_vector_type(8)));
typedef float f32x4  __attribute__((ext_vector_type(4)));

#define CAP 6

// ws layout (bytes)
#define WS_LOSS 0
#define WS_DONE 8
#define WS_EBF  64        // 1024*64 bf16 (permuted) = 131072 B -> ends 131136
#define WS_MARG 131136    // 65536 floats = 262144 B -> ends 393280
#define WS_CNT  393280    // 131072 ints = 524288 B -> ends 917568
#define WS_CAND 917568    // 131072*CAP ushorts = 1572864 B -> ends 2490432

__device__ __forceinline__ unsigned short f2bf(float f) {
    unsigned u = __float_as_uint(f);
    return (unsigned short)((u + 0x7fffu + ((u >> 16) & 1u)) >> 16);  // RTNE
}

// numpy pairwise sum-of-squares (n=64), exact op order (R2-proven):
// r[j] += a[i+j]^2 (8 accs), then ((r0+r1)+(r2+r3))+((r4+r5)+(r6+r7)).
__device__ __forceinline__ float np_pairwise_sumsq64_p(const float* __restrict__ a) {
    float r[8];
    #pragma unroll
    for (int i = 0; i < 64; i += 8)
        #pragma unroll
        for (int jj = 0; jj < 2; ++jj) {
            float4 v = *(const float4*)(a + i + jj * 4);
            float vv[4] = {v.x, v.y, v.z, v.w};
            #pragma unroll
            for (int m = 0; m < 4; ++m) {
                int j = jj * 4 + m;
                float sq = __fmul_rn(vv[m], vv[m]);
                r[j] = (i == 0) ? sq : __fadd_rn(r[j], sq);
            }
        }
    return __fadd_rn(
        __fadd_rn(__fadd_rn(r[0], r[1]), __fadd_rn(r[2], r[3])),
        __fadd_rn(__fadd_rn(r[4], r[5]), __fadd_rn(r[6], r[7])));
}

// exact numpy fp32 score of (z, code k): round(znorm+enorm) - 2*dot (R2-proven)
__device__ __forceinline__ float exact_score(const float* __restrict__ z, float znorm,
                                             const float* __restrict__ emb, int k) {
    const float* ep = emb + k * 64;
    float en = np_pairwise_sumsq64_p(ep);
    float acc = 0.0f;
    #pragma unroll
    for (int j = 0; j < 16; ++j) {
        float4 v = *(const float4*)(ep + j * 4);
        acc = fmaf(z[4*j+0], v.x, acc);
        acc = fmaf(z[4*j+1], v.y, acc);
        acc = fmaf(z[4*j+2], v.z, acc);
        acc = fmaf(z[4*j+3], v.w, acc);
    }
    return __fsub_rn(__fadd_rn(znorm, en), __fmul_rn(2.0f, acc));
}

// K1: zero loss/done/cnt; bf16 codebook (MFMA-B-permuted); per-position margins.
// ebf[tile(64)][chunk j(8)][row r(16)][8 bf16], code = tile*16+r.
__global__ __launch_bounds__(256) void prep_kernel(
    const float* __restrict__ ze, const float* __restrict__ emb,
    unsigned short* __restrict__ ebf, float* __restrict__ marg,
    float* __restrict__ loss, int* __restrict__ done, int* __restrict__ cnt)
{
    int gid = blockIdx.x * 256 + threadIdx.x;   // grid 512*256 = 131072
    if (gid == 0) { *loss = 0.0f; *done = 0; }
    cnt[gid] = 0;
    if (gid < 65536) {
        // margin for position gid (R5-R7-proven formula)
        const float* zp = ze + ((gid >> 12) * 262144 + (gid & 4095));
        float S = 0.0f;
        #pragma unroll
        for (int l = 0; l < 64; ++l) S += fabsf(zp[l * 4096]);
        marg[gid] = 1.67e-5f * S + 2.0e-4f;
    }
    if (gid < 1024) {
        int k = gid;
        float e[64];
        #pragma unroll
        for (int l = 0; l < 64; ++l) e[l] = emb[k * 64 + l];
        int tile = k >> 4, r = k & 15;
        #pragma unroll
        for (int j = 0; j < 8; ++j) {
            bf16x8 v;
            #pragma unroll
            for (int m = 0; m < 8; ++m) v[m] = (short)f2bf(e[j * 8 + m]);
            *(bf16x8*)(ebf + tile * 1024 + j * 128 + r * 8) = v;
        }
    }
}

// K2: MFMA filter. Grid 1024 = 512 position-blocks x 2 K-halves (kh=blk&1).
// Block = 128 positions x 512 codes; half codebook in static LDS (64 KB ->
// 2 blocks/CU, 8 waves/CU). One barrier. Per-half threshold = half rowmax
// - marg/2 (superset of global candidate set).
__global__ __launch_bounds__(256) void vq_filter_kernel(
    const float* __restrict__ ze, const unsigned short* __restrict__ ebf,
    const float* __restrict__ marg,
    int* __restrict__ cnt, unsigned short* __restrict__ cand)
{
    __shared__ __align__(16) unsigned short ebf_l[32768];   // exactly 64 KB

    const int t = threadIdx.x;
    const int kh = blockIdx.x & 1;
    const int n0 = (blockIdx.x >> 1) * 128;
    const int gbase = (n0 >> 12) * 262144 + (n0 & 4095);

    const int wv = t >> 6, lane = t & 63;
    const int r = lane & 15, q = lane >> 4;
    const int wp = wv * 32;

    // A-fragments from global ze (A[m=lane&15][k=q*8+j], R7-proven build)
    bf16x8 a0[2], a1[2];
    #pragma unroll
    for (int rg = 0; rg < 2; ++rg) {
        const float* zb = ze + gbase + wp + rg * 16 + r;
        #pragma unroll
        for (int j = 0; j < 8; ++j) {
            a0[rg][j] = (short)f2bf(zb[(q * 8 + j) * 4096]);
            a1[rg][j] = (short)f2bf(zb[(32 + q * 8 + j) * 4096]);
        }
    }

    // stage half codebook (65536 B): tiles kh*32 .. kh*32+31 contiguous
    {
        const bf16x8* src = (const bf16x8*)(ebf + kh * 32768);
        bf16x8* dst = (bf16x8*)ebf_l;
        #pragma unroll 8
        for (int i = 0; i < 16; ++i) dst[t + i * 256] = src[t + i * 256];
    }
    __syncthreads();

    const unsigned short* bptr = ebf_l + q * 128 + r * 8;

    // ---- pass 1: per-row max of c = z.e over this half's 512 codes ----
    float rm[8];
    #pragma unroll
    for (int i = 0; i < 8; ++i) rm[i] = -1e30f;
    {
        bf16x8 pb0[2], pb1[2];
        pb0[0] = *(const bf16x8*)(bptr);
        pb1[0] = *(const bf16x8*)(bptr + 512);
        pb0[1] = *(const bf16x8*)(bptr + 1024);
        pb1[1] = *(const bf16x8*)(bptr + 1536);
        #pragma unroll 4
        for (int tile = 0; tile < 32; ++tile) {
            bf16x8 b0 = pb0[tile & 1], b1 = pb1[tile & 1];
            int nt = tile + 2; if (nt > 31) nt = 31;
            pb0[tile & 1] = *(const bf16x8*)(bptr + nt * 1024);
            pb1[tile & 1] = *(const bf16x8*)(bptr + nt * 1024 + 512);
            #pragma unroll
            for (int rg = 0; rg < 2; ++rg) {
                f32x4 c = {0.f, 0.f, 0.f, 0.f};
                c = __builtin_amdgcn_mfma_f32_16x16x32_bf16(a0[rg], b0, c, 0, 0, 0);
                c = __builtin_amdgcn_mfma_f32_16x16x32_bf16(a1[rg], b1, c, 0, 0, 0);
                #pragma unroll
                for (int i = 0; i < 4; ++i)
                    rm[rg * 4 + i] = fmaxf(rm[rg * 4 + i], c[i]);
            }
        }
    }
    float thr[8];
    #pragma unroll
    for (int j = 0; j < 8; ++j) {
        float v = rm[j];
        v = fmaxf(v, __shfl_xor(v, 1, 16));
        v = fmaxf(v, __shfl_xor(v, 2, 16));
        v = fmaxf(v, __shfl_xor(v, 4, 16));
        v = fmaxf(v, __shfl_xor(v, 8, 16));
        int row = wp + (j >> 2) * 16 + q * 4 + (j & 3);
        thr[j] = v - 0.5f * marg[n0 + row];
    }

    // ---- pass 2: collect candidates into global ws ----
    {
        bf16x8 pb0[2], pb1[2];
        pb0[0] = *(const bf16x8*)(bptr);
        pb1[0] = *(const bf16x8*)(bptr + 512);
        pb0[1] = *(const bf16x8*)(bptr + 1024);
        pb1[1] = *(const bf16x8*)(bptr + 1536);
        #pragma unroll 4
        for (int tile = 0; tile < 32; ++tile) {
            bf16x8 b0 = pb0[tile & 1], b1 = pb1[tile & 1];
            int nt = tile + 2; if (nt > 31) nt = 31;
            pb0[tile & 1] = *(const bf16x8*)(bptr + nt * 1024);
            pb1[tile & 1] = *(const bf16x8*)(bptr + nt * 1024 + 512);
            int code = kh * 512 + tile * 16 + r;
            #pragma unroll
            for (int rg = 0; rg < 2; ++rg) {
                f32x4 c = {0.f, 0.f, 0.f, 0.f};
                c = __builtin_amdgcn_mfma_f32_16x16x32_bf16(a0[rg], b0, c, 0, 0, 0);
                c = __builtin_amdgcn_mfma_f32_16x16x32_bf16(a1[rg], b1, c, 0, 0, 0);
                #pragma unroll
                for (int i = 0; i < 4; ++i) {
                    if (c[i] >= thr[rg * 4 + i]) {
                        int gp = n0 + wp + rg * 16 + q * 4 + i;
                        int ci = atomicAdd(&cnt[gp * 2 + kh], 1);
                        if (ci < CAP) cand[(gp * 2 + kh) * CAP + ci] = (unsigned short)code;
                    }
                }
            }
        }
    }
}

// K3: exact fp32 numpy rescore + select + z_q/loss epilogue + finalize.
__global__ __launch_bounds__(256) void rescore_kernel(
    const float* __restrict__ ze, const float* __restrict__ emb,
    const int* __restrict__ cnt, const unsigned short* __restrict__ cand,
    float* __restrict__ out_zq, float* __restrict__ out_idxf,
    float* __restrict__ loss, int* __restrict__ done,
    float* __restrict__ out_loss)
{
    const int t = threadIdx.x;
    const int n0 = blockIdx.x * 256;
    const int gbase = (n0 >> 12) * 262144 + (n0 & 4095);
    const int n = n0 + t;

    float z[64];
    const float* zp = ze + gbase + t;
    #pragma unroll
    for (int l = 0; l < 64; ++l) z[l] = zp[l * 4096];
    const float znorm = np_pairwise_sumsq64_p(z);

    int c0 = cnt[n * 2], c1 = cnt[n * 2 + 1];
    float best = 1e30f; int bk = 1 << 20;
    if (c0 <= CAP && c1 <= CAP) {
        for (int i = 0; i < c0; ++i) {
            int k = cand[(n * 2) * CAP + i];
            float sc = exact_score(z, znorm, emb, k);
            if (sc < best || (sc == best && k < bk)) { best = sc; bk = k; }
        }
        for (int i = 0; i < c1; ++i) {
            int k = cand[(n * 2 + 1) * CAP + i];
            float sc = exact_score(z, znorm, emb, k);
            if (sc < best || (sc == best && k < bk)) { best = sc; bk = k; }
        }
    } else {
        // overflow fallback: exact full scan (numpy first-occurrence argmin)
        for (int k = 0; k < 1024; ++k) {
            float sc = exact_score(z, znorm, emb, k);
            if (sc < best) { best = sc; bk = k; }
        }
    }
    out_idxf[n] = (float)bk;

    // epilogue: z_q gather + loss partial
    {
        const float* er = emb + bk * 64;
        float ls = 0.0f;
        #pragma unroll
        for (int j = 0; j < 16; ++j) {
            float4 v = *(const float4*)(er + j * 4);
            float vv[4] = {v.x, v.y, v.z, v.w};
            #pragma unroll
            for (int m = 0; m < 4; ++m) {
                int l = 4 * j + m;
                out_zq[gbase + t + l * 4096] = vv[m];
                float d = vv[m] - z[l];
                ls = fmaf(d, d, ls);
            }
        }
        #pragma unroll
        for (int off = 32; off > 0; off >>= 1) ls += __shfl_down(ls, off, 64);
        if ((t & 63) == 0) atomicAdd(loss, ls);
    }

    __syncthreads();
    if (t == 0) {
        __threadfence();
        int old = atomicAdd(done, 1);
        if (old == (int)gridDim.x - 1) {
            __threadfence();
            float total = atomicAdd(loss, 0.0f);   // coherent read
            *out_loss = 1.25f * total / 4194304.0f;
        }
    }
}

extern "C" void kernel_launch(void* const* d_in, const int* in_sizes, int n_in,
                              void* d_out, int out_size, void* d_ws, size_t ws_size,
                              hipStream_t stream)
{
    const float* ze  = (const float*)d_in[0];   // (16,64,64,64) fp32
    const float* emb = (const float*)d_in[1];   // (1024,64) fp32
    float* out = (float*)d_out;
    float* out_zq   = out;                 // 4194304
    float* out_loss = out + 4194304;       // 1
    float* out_idxf = out + 4194305;       // 65536

    char* w = (char*)d_ws;
    float*          ws_loss = (float*)(w + WS_LOSS);
    int*            ws_done = (int*)(w + WS_DONE);
    unsigned short* ebf     = (unsigned short*)(w + WS_EBF);
    float*          ws_marg = (float*)(w + WS_MARG);
    int*            ws_cnt  = (int*)(w + WS_CNT);
    unsigned short* ws_cand = (unsigned short*)(w + WS_CAND);

    prep_kernel<<<512, 256, 0, stream>>>(ze, emb, ebf, ws_marg, ws_loss, ws_done, ws_cnt);
    vq_filter_kernel<<<1024, 256, 0, stream>>>(ze, ebf, ws_marg, ws_cnt, ws_cand);
    rescore_kernel<<<256, 256, 0, stream>>>(ze, emb, ws_cnt, ws_cand,
                                            out_zq, out_idxf, ws_loss, ws_done, out_loss);
}

// Round 10
// 190.368 us; speedup vs baseline: 3.7238x; 3.7238x over previous
//
#include <hip/hip_runtime.h>

typedef short bf16x8 __attribute__((ext_vector_type(8)));
typedef float f32x4  __attribute__((ext_vector_type(4)));

#define CAP 8

// ws layout (bytes)
#define WS_LOSS 0
#define WS_DONE 8
#define WS_EBF  64        // 1024*64 bf16 (permuted) = 131072 B -> ends 131136
#define WS_MARG 131136    // 65536 floats = 262144 B -> ends 393280
#define WS_CNT  393280    // 131072 ints = 524288 B -> ends 917568
#define WS_CAND 917568    // 131072*CAP ushorts = 2097152 B -> ends 3014720

__device__ __forceinline__ unsigned short f2bf(float f) {
    unsigned u = __float_as_uint(f);
    return (unsigned short)((u + 0x7fffu + ((u >> 16) & 1u)) >> 16);  // RTNE
}

// numpy pairwise sum-of-squares (n=64), exact op order (R2-proven):
// r[j] += a[i+j]^2 (8 accs), then ((r0+r1)+(r2+r3))+((r4+r5)+(r6+r7)).
__device__ __forceinline__ float np_pairwise_sumsq64_p(const float* __restrict__ a) {
    float r[8];
    #pragma unroll
    for (int i = 0; i < 64; i += 8)
        #pragma unroll
        for (int jj = 0; jj < 2; ++jj) {
            float4 v = *(const float4*)(a + i + jj * 4);
            float vv[4] = {v.x, v.y, v.z, v.w};
            #pragma unroll
            for (int m = 0; m < 4; ++m) {
                int j = jj * 4 + m;
                float sq = __fmul_rn(vv[m], vv[m]);
                r[j] = (i == 0) ? sq : __fadd_rn(r[j], sq);
            }
        }
    return __fadd_rn(
        __fadd_rn(__fadd_rn(r[0], r[1]), __fadd_rn(r[2], r[3])),
        __fadd_rn(__fadd_rn(r[4], r[5]), __fadd_rn(r[6], r[7])));
}

// exact numpy fp32 score of (z, code k): round(znorm+enorm) - 2*dot (R2-proven)
__device__ __forceinline__ float exact_score(const float* __restrict__ z, float znorm,
                                             const float* __restrict__ emb, int k) {
    const float* ep = emb + k * 64;
    float en = np_pairwise_sumsq64_p(ep);
    float acc = 0.0f;
    #pragma unroll
    for (int j = 0; j < 16; ++j) {
        float4 v = *(const float4*)(ep + j * 4);
        acc = fmaf(z[4*j+0], v.x, acc);
        acc = fmaf(z[4*j+1], v.y, acc);
        acc = fmaf(z[4*j+2], v.z, acc);
        acc = fmaf(z[4*j+3], v.w, acc);
    }
    return __fsub_rn(__fadd_rn(znorm, en), __fmul_rn(2.0f, acc));
}

// K1: zero loss/done/cnt; bf16 codebook (MFMA-B-permuted); per-position margins.
__global__ __launch_bounds__(256) void prep_kernel(
    const float* __restrict__ ze, const float* __restrict__ emb,
    unsigned short* __restrict__ ebf, float* __restrict__ marg,
    float* __restrict__ loss, int* __restrict__ done, int* __restrict__ cnt)
{
    int gid = blockIdx.x * 256 + threadIdx.x;   // grid 512*256 = 131072
    if (gid == 0) { *loss = 0.0f; *done = 0; }
    cnt[gid] = 0;
    if (gid < 65536) {
        const float* zp = ze + ((gid >> 12) * 262144 + (gid & 4095));
        float S = 0.0f;
        #pragma unroll
        for (int l = 0; l < 64; ++l) S += fabsf(zp[l * 4096]);
        marg[gid] = 1.67e-5f * S + 2.0e-4f;   // R5-R9-proven bound
    }
    if (gid < 1024) {
        int k = gid;
        float e[64];
        #pragma unroll
        for (int l = 0; l < 64; ++l) e[l] = emb[k * 64 + l];
        int tile = k >> 4, r = k & 15;
        #pragma unroll
        for (int j = 0; j < 8; ++j) {
            bf16x8 v;
            #pragma unroll
            for (int m = 0; m < 8; ++m) v[m] = (short)f2bf(e[j * 8 + m]);
            *(bf16x8*)(ebf + tile * 1024 + j * 128 + r * 8) = v;
        }
    }
}

// K2: MFMA filter. Grid 1024 = 512 position-blocks x 2 K-halves (kh=blk&1).
// Block = 128 positions x 512 codes; half codebook in static LDS (64 KB ->
// 2 blocks/CU, 8 waves/CU). One barrier. Per-half threshold = half rowmax
// - marg/2 (superset of the global candidate set).
__global__ __launch_bounds__(256) void vq_filter_kernel(
    const float* __restrict__ ze, const unsigned short* __restrict__ ebf,
    const float* __restrict__ marg,
    int* __restrict__ cnt, unsigned short* __restrict__ cand)
{
    __shared__ __align__(16) unsigned short ebf_l[32768];   // exactly 64 KB

    const int t = threadIdx.x;
    const int kh = blockIdx.x & 1;
    const int n0 = (blockIdx.x >> 1) * 128;
    const int gbase = (n0 >> 12) * 262144 + (n0 & 4095);

    const int wv = t >> 6, lane = t & 63;
    const int r = lane & 15, q = lane >> 4;
    const int wp = wv * 32;

    // A-fragments from global ze (A[m=lane&15][k=q*8+j], R7-proven build)
    bf16x8 a0[2], a1[2];
    #pragma unroll
    for (int rg = 0; rg < 2; ++rg) {
        const float* zb = ze + gbase + wp + rg * 16 + r;
        #pragma unroll
        for (int j = 0; j < 8; ++j) {
            a0[rg][j] = (short)f2bf(zb[(q * 8 + j) * 4096]);
            a1[rg][j] = (short)f2bf(zb[(32 + q * 8 + j) * 4096]);
        }
    }

    // stage half codebook (65536 B): tiles kh*32 .. kh*32+31 contiguous
    {
        const bf16x8* src = (const bf16x8*)(ebf + kh * 32768);
        bf16x8* dst = (bf16x8*)ebf_l;
        #pragma unroll 8
        for (int i = 0; i < 16; ++i) dst[t + i * 256] = src[t + i * 256];
    }
    __syncthreads();

    const unsigned short* bptr = ebf_l + q * 128 + r * 8;

    // ---- pass 1: per-row max of c = z.e over this half's 512 codes ----
    float rm[8];
    #pragma unroll
    for (int i = 0; i < 8; ++i) rm[i] = -1e30f;
    {
        bf16x8 pb0[2], pb1[2];
        pb0[0] = *(const bf16x8*)(bptr);
        pb1[0] = *(const bf16x8*)(bptr + 512);
        pb0[1] = *(const bf16x8*)(bptr + 1024);
        pb1[1] = *(const bf16x8*)(bptr + 1536);
        #pragma unroll 4
        for (int tile = 0; tile < 32; ++tile) {
            bf16x8 b0 = pb0[tile & 1], b1 = pb1[tile & 1];
            int nt = tile + 2; if (nt > 31) nt = 31;
            pb0[tile & 1] = *(const bf16x8*)(bptr + nt * 1024);
            pb1[tile & 1] = *(const bf16x8*)(bptr + nt * 1024 + 512);
            #pragma unroll
            for (int rg = 0; rg < 2; ++rg) {
                f32x4 c = {0.f, 0.f, 0.f, 0.f};
                c = __builtin_amdgcn_mfma_f32_16x16x32_bf16(a0[rg], b0, c, 0, 0, 0);
                c = __builtin_amdgcn_mfma_f32_16x16x32_bf16(a1[rg], b1, c, 0, 0, 0);
                #pragma unroll
                for (int i = 0; i < 4; ++i)
                    rm[rg * 4 + i] = fmaxf(rm[rg * 4 + i], c[i]);
            }
        }
    }
    float thr[8];
    #pragma unroll
    for (int j = 0; j < 8; ++j) {
        float v = rm[j];
        v = fmaxf(v, __shfl_xor(v, 1, 16));
        v = fmaxf(v, __shfl_xor(v, 2, 16));
        v = fmaxf(v, __shfl_xor(v, 4, 16));
        v = fmaxf(v, __shfl_xor(v, 8, 16));
        int row = wp + (j >> 2) * 16 + q * 4 + (j & 3);
        thr[j] = v - 0.5f * marg[n0 + row];
    }

    // ---- pass 2: collect candidates into global ws ----
    {
        bf16x8 pb0[2], pb1[2];
        pb0[0] = *(const bf16x8*)(bptr);
        pb1[0] = *(const bf16x8*)(bptr + 512);
        pb0[1] = *(const bf16x8*)(bptr + 1024);
        pb1[1] = *(const bf16x8*)(bptr + 1536);
        #pragma unroll 4
        for (int tile = 0; tile < 32; ++tile) {
            bf16x8 b0 = pb0[tile & 1], b1 = pb1[tile & 1];
            int nt = tile + 2; if (nt > 31) nt = 31;
            pb0[tile & 1] = *(const bf16x8*)(bptr + nt * 1024);
            pb1[tile & 1] = *(const bf16x8*)(bptr + nt * 1024 + 512);
            int code = kh * 512 + tile * 16 + r;
            #pragma unroll
            for (int rg = 0; rg < 2; ++rg) {
                f32x4 c = {0.f, 0.f, 0.f, 0.f};
                c = __builtin_amdgcn_mfma_f32_16x16x32_bf16(a0[rg], b0, c, 0, 0, 0);
                c = __builtin_amdgcn_mfma_f32_16x16x32_bf16(a1[rg], b1, c, 0, 0, 0);
                #pragma unroll
                for (int i = 0; i < 4; ++i) {
                    if (c[i] >= thr[rg * 4 + i]) {
                        int gp = n0 + wp + rg * 16 + q * 4 + i;
                        int ci = atomicAdd(&cnt[gp * 2 + kh], 1);
                        if (ci < CAP) cand[(gp * 2 + kh) * CAP + ci] = (unsigned short)code;
                    }
                }
            }
        }
    }
}

// K3: exact fp32 numpy rescore + select + z_q/loss epilogue + finalize.
// Overflowed positions handled block-cooperatively (no serial 1024-scan tail).
__global__ __launch_bounds__(256) void rescore_kernel(
    const float* __restrict__ ze, const float* __restrict__ emb,
    const int* __restrict__ cnt, const unsigned short* __restrict__ cand,
    float* __restrict__ out_zq, float* __restrict__ out_idxf,
    float* __restrict__ loss, int* __restrict__ done,
    float* __restrict__ out_loss)
{
    __shared__ int   ovf_list[256];
    __shared__ int   ovf_cnt;
    __shared__ float zsh[64];
    __shared__ float znorm_sh;
    __shared__ float red_s[256];
    __shared__ int   red_k[256];
    __shared__ int   res_k[256];

    const int t = threadIdx.x;
    const int n0 = blockIdx.x * 256;
    const int gbase = (n0 >> 12) * 262144 + (n0 & 4095);
    const int n = n0 + t;
    if (t == 0) ovf_cnt = 0;
    __syncthreads();

    float z[64];
    const float* zp = ze + gbase + t;
    #pragma unroll
    for (int l = 0; l < 64; ++l) z[l] = zp[l * 4096];
    const float znorm = np_pairwise_sumsq64_p(z);

    int c0 = cnt[n * 2], c1 = cnt[n * 2 + 1];
    float best = 1e30f; int bk = 1 << 20;
    if (c0 <= CAP && c1 <= CAP) {
        for (int i = 0; i < c0; ++i) {
            int k = cand[(n * 2) * CAP + i];
            float sc = exact_score(z, znorm, emb, k);
            if (sc < best || (sc == best && k < bk)) { best = sc; bk = k; }
        }
        for (int i = 0; i < c1; ++i) {
            int k = cand[(n * 2 + 1) * CAP + i];
            float sc = exact_score(z, znorm, emb, k);
            if (sc < best || (sc == best && k < bk)) { best = sc; bk = k; }
        }
    } else {
        int pos = atomicAdd(&ovf_cnt, 1);
        ovf_list[pos] = t;
    }
    res_k[t] = bk;
    __syncthreads();

    // ---- block-cooperative exact full scan for overflowed positions ----
    const int no = ovf_cnt;
    for (int i = 0; i < no; ++i) {
        const int p = ovf_list[i];
        if (t == p) {
            #pragma unroll
            for (int l = 0; l < 64; ++l) zsh[l] = z[l];
            znorm_sh = znorm;
        }
        __syncthreads();
        float b2 = 1e30f; int k2 = 1 << 20;
        #pragma unroll
        for (int j = 0; j < 4; ++j) {
            int k = t + j * 256;   // ascending within thread -> lowest-k on tie
            float sc = exact_score(zsh, znorm_sh, emb, k);
            if (sc < b2) { b2 = sc; k2 = k; }
        }
        red_s[t] = b2; red_k[t] = k2;
        __syncthreads();
        for (int st = 128; st > 0; st >>= 1) {
            if (t < st) {
                float os = red_s[t + st]; int ok = red_k[t + st];
                if (os < red_s[t] || (os == red_s[t] && ok < red_k[t])) {
                    red_s[t] = os; red_k[t] = ok;
                }
            }
            __syncthreads();
        }
        if (t == 0) res_k[p] = red_k[0];
        __syncthreads();
    }

    bk = res_k[t];
    out_idxf[n] = (float)bk;

    // epilogue: z_q gather + loss partial
    {
        const float* er = emb + bk * 64;
        float ls = 0.0f;
        #pragma unroll
        for (int j = 0; j < 16; ++j) {
            float4 v = *(const float4*)(er + j * 4);
            float vv[4] = {v.x, v.y, v.z, v.w};
            #pragma unroll
            for (int m = 0; m < 4; ++m) {
                int l = 4 * j + m;
                out_zq[gbase + t + l * 4096] = vv[m];
                float d = vv[m] - z[l];
                ls = fmaf(d, d, ls);
            }
        }
        #pragma unroll
        for (int off = 32; off > 0; off >>= 1) ls += __shfl_down(ls, off, 64);
        if ((t & 63) == 0) atomicAdd(loss, ls);
    }

    __syncthreads();
    if (t == 0) {
        __threadfence();
        int old = atomicAdd(done, 1);
        if (old == (int)gridDim.x - 1) {
            __threadfence();
            float total = atomicAdd(loss, 0.0f);   // coherent read
            *out_loss = 1.25f * total / 4194304.0f;
        }
    }
}

extern "C" void kernel_launch(void* const* d_in, const int* in_sizes, int n_in,
                              void* d_out, int out_size, void* d_ws, size_t ws_size,
                              hipStream_t stream)
{
    const float* ze  = (const float*)d_in[0];   // (16,64,64,64) fp32
    const float* emb = (const float*)d_in[1];   // (1024,64) fp32
    float* out = (float*)d_out;
    float* out_zq   = out;                 // 4194304
    float* out_loss = out + 4194304;       // 1
    float* out_idxf = out + 4194305;       // 65536

    char* w = (char*)d_ws;
    float*          ws_loss = (float*)(w + WS_LOSS);
    int*            ws_done = (int*)(w + WS_DONE);
    unsigned short* ebf     = (unsigned short*)(w + WS_EBF);
    float*          ws_marg = (float*)(w + WS_MARG);
    int*            ws_cnt  = (int*)(w + WS_CNT);
    unsigned short* ws_cand = (unsigned short*)(w + WS_CAND);

    prep_kernel<<<512, 256, 0, stream>>>(ze, emb, ebf, ws_marg, ws_loss, ws_done, ws_cnt);
    vq_filter_kernel<<<1024, 256, 0, stream>>>(ze, ebf, ws_marg, ws_cnt, ws_cand);
    rescore_kernel<<<256, 256, 0, stream>>>(ze, emb, ws_cnt, ws_cand,
                                            out_zq, out_idxf, ws_loss, ws_done, out_loss);
}